// Round 11
// baseline (209.078 us; speedup 1.0000x reference)
//
#include <hip/hip_runtime.h>
#include <hip/hip_bf16.h>
#include <math.h>

// Problem constants (from reference)
#define N_NODES 50000
#define N_EDGES 800000
#define E_TOT   (N_EDGES + N_NODES)   // edges + self loops = 850000
#define HID     128
#define N_GRAPHS 64
#define NEG_SLOPE 0.2f

// Radix partition params
#define NBKT 196                      // buckets of 256 dst nodes
#define CAPB 6144                     // fixed bucket capacity (mean 4337, +27 sigma)
#define CHUNK3 4096
#define NB3  ((E_TOT + CHUNK3 - 1) / CHUNK3)    // 208
#define NBG  ((N_NODES + 127) / 128)            // 391 gemm blocks (128-row tiles)

typedef __attribute__((ext_vector_type(8))) short bf16x8;
typedef __attribute__((ext_vector_type(4))) float f32x4;
typedef __attribute__((ext_vector_type(2))) float f32x2;

__device__ __forceinline__ ushort f2bf(float f) {
    union { float f; uint u; } x; x.f = f;
    uint r = x.u + 0x7fffu + ((x.u >> 16) & 1u);   // round-to-nearest-even
    return (ushort)(r >> 16);
}
__device__ __forceinline__ float bfbits2f(uint bits_hi) {
    union { uint u; float f; } x; x.u = bits_hi;
    return x.f;
}

// ---------------------------------------------------------------------------
// Prep: weight convert+transpose, gcur zero, graph bounds, row_start[N]=E_TOT.
// ---------------------------------------------------------------------------
__global__ __launch_bounds__(256) void prep(const float* __restrict__ W1,
                                            const float* __restrict__ W2,
                                            ushort* __restrict__ Wt1,
                                            ushort* __restrict__ Wt2,
                                            int* __restrict__ gcur,
                                            const int* __restrict__ batch,
                                            int* __restrict__ gstart,
                                            int* __restrict__ row_start) {
    int tid = threadIdx.x;
    if (blockIdx.x < 192) {
        int idx = blockIdx.x * 256 + tid;
        if (idx < 256 * 128) {
            int k = idx >> 7, n = idx & 127;
            Wt1[n * 256 + k] = f2bf(W1[idx]);
        } else if (idx < 256 * 128 + 128 * 128) {
            int j = idx - 256 * 128;
            int k = j >> 7, n = j & 127;
            Wt2[n * 128 + k] = f2bf(W2[j]);
        }
        if (idx <= NBKT) gcur[idx] = 0;
        if (idx == 0) row_start[N_NODES] = E_TOT;
    } else {
        int i = (blockIdx.x - 192) * 256 + tid;
        if (i >= N_NODES) return;
        int b  = batch[i];
        int bp = (i == 0) ? -1 : batch[i - 1];
        for (int g = bp + 1; g <= b; g++) gstart[g] = i;
        if (i == N_NODES - 1) {
            for (int g = b + 1; g <= N_GRAPHS; g++) gstart[g] = N_NODES;
        }
    }
}

// ---------------------------------------------------------------------------
// Fused dispatch (512 threads): blocks 0..NBG-1 layer-1 GEMM (128x128 tile,
// fp32 A, K=256, fp8 C + fused alpha); blocks NBG.. bin_scatter.
// ---------------------------------------------------------------------------
__global__ __launch_bounds__(512) void gemm1_scatter(const float* __restrict__ A,
                                                     const ushort* __restrict__ Wt,
                                                     unsigned char* __restrict__ C8,
                                                     const float* __restrict__ a_sv,
                                                     const float* __restrict__ a_dv,
                                                     float* __restrict__ alpha_s,
                                                     float* __restrict__ alpha_d,
                                                     const int* __restrict__ edge_src,
                                                     const int* __restrict__ edge_dst,
                                                     int* __restrict__ gcur,
                                                     uint* __restrict__ staged) {
    __shared__ char smem[36864];
    int tid = threadIdx.x;

    if (blockIdx.x < NBG) {
        constexpr int K = 256, KC = 64, AP = 72;
        ushort* As = (ushort*)smem;                 // 128x72 bf16 = 18432 B
        ushort* Bs = (ushort*)(smem + 18432);       // 128x72 bf16 = 18432 B
        int lane = tid & 63;
        int wv = tid >> 6;          // 0..7; wave handles rows wv*16..wv*16+15
        int mrow = lane & 15;
        int quad = lane >> 4;
        int row0 = blockIdx.x * 128;
        int M = N_NODES;

        f32x4 acc[8];
#pragma unroll
        for (int t = 0; t < 8; t++) acc[t] = (f32x4){0.f, 0.f, 0.f, 0.f};

        for (int k0 = 0; k0 < K; k0 += KC) {
            // A tile: 128 rows x 64 k fp32 -> bf16 (1024 chunks of 8)
#pragma unroll
            for (int p = 0; p < 2; p++) {
                int c = p * 512 + tid;
                int r = c >> 3;
                int kk = (c & 7) * 8;
                int grow = row0 + r;
                float4 v0 = make_float4(0.f, 0.f, 0.f, 0.f);
                float4 v1 = v0;
                if (grow < M) {
                    const float* src = &A[(size_t)grow * K + k0 + kk];
                    v0 = *(const float4*)src;
                    v1 = *(const float4*)(src + 4);
                }
                uint4 w;
                w.x = (uint)f2bf(v0.x) | ((uint)f2bf(v0.y) << 16);
                w.y = (uint)f2bf(v0.z) | ((uint)f2bf(v0.w) << 16);
                w.z = (uint)f2bf(v1.x) | ((uint)f2bf(v1.y) << 16);
                w.w = (uint)f2bf(v1.z) | ((uint)f2bf(v1.w) << 16);
                *(uint4*)&As[r * AP + kk] = w;
            }
            // B tile: 128 n x 64 k bf16 (1024 chunks of 8)
#pragma unroll
            for (int p = 0; p < 2; p++) {
                int c = p * 512 + tid;
                int n = c >> 3;
                int kk = (c & 7) * 8;
                uint4 v = *(const uint4*)&Wt[(size_t)n * K + k0 + kk];
                *(uint4*)&Bs[n * AP + kk] = v;
            }
            __syncthreads();

            const ushort* arow = &As[(wv * 16 + mrow) * AP + quad * 8];
            const ushort* brow = &Bs[mrow * AP + quad * 8];
#pragma unroll
            for (int ks = 0; ks < KC; ks += 32) {
                bf16x8 a = *(const bf16x8*)&arow[ks];
#pragma unroll
                for (int t = 0; t < 8; t++) {
                    bf16x8 b = *(const bf16x8*)&brow[t * 16 * AP + ks];
                    acc[t] = __builtin_amdgcn_mfma_f32_16x16x32_bf16(a, b, acc[t], 0, 0, 0);
                }
            }
            __syncthreads();
        }

        float as_r[8], ad_r[8];
#pragma unroll
        for (int t = 0; t < 8; t++) {
            int col = t * 16 + mrow;
            as_r[t] = a_sv[col];
            ad_r[t] = a_dv[col];
        }
#pragma unroll
        for (int r = 0; r < 4; r++) {
            float ps = 0.f, pd = 0.f;
#pragma unroll
            for (int t = 0; t < 8; t++) {
                ps = fmaf(acc[t][r], as_r[t], ps);
                pd = fmaf(acc[t][r], ad_r[t], pd);
            }
#pragma unroll
            for (int o = 1; o < 16; o <<= 1) {
                ps += __shfl_xor(ps, o, 64);
                pd += __shfl_xor(pd, o, 64);
            }
            int row = row0 + wv * 16 + quad * 4 + r;
            if (mrow == 0 && row < M) {
                alpha_s[row] = ps;
                alpha_d[row] = pd;
            }
        }
#pragma unroll
        for (int t = 0; t < 8; t++) {
#pragma unroll
            for (int r = 0; r < 4; r++) {
                int row = row0 + wv * 16 + quad * 4 + r;
                if (row < M) {
                    float vv = acc[t][r];
                    uint p8 = (uint)__builtin_amdgcn_cvt_pk_fp8_f32(vv, vv, 0, false);
                    C8[(size_t)row * HID + t * 16 + mrow] = (unsigned char)(p8 & 0xFF);
                }
            }
        }
    } else {
        // ---------------- bin_scatter path (512 threads) ----------------
        int* hist    = (int*)smem;
        int* scan_s  = hist + 256;
        int* base_l  = scan_s + 256;
        int* cur     = base_l + 256;
        int* runbase = cur + 256;
        uint* vals   = (uint*)(runbase + 256);    // 16 KB

        int e0 = (blockIdx.x - NBG) * CHUNK3;
        int cnt = min(CHUNK3, E_TOT - e0);

        if (tid < 256) hist[tid] = 0;
        __syncthreads();
        for (int i = tid; i < cnt; i += 512) {
            int e = e0 + i;
            int d = (e < N_EDGES) ? edge_dst[e] : (e - N_EDGES);
            atomicAdd(&hist[d >> 8], 1);
        }
        __syncthreads();
        int v = 0;
        if (tid < 256) { v = hist[tid]; scan_s[tid] = v; }
        __syncthreads();
        for (int off = 1; off < 256; off <<= 1) {
            int t = (tid < 256 && tid >= off) ? scan_s[tid - off] : 0;
            __syncthreads();
            if (tid < 256) scan_s[tid] += t;
            __syncthreads();
        }
        if (tid < 256) {
            base_l[tid] = scan_s[tid] - v;
            cur[tid] = scan_s[tid] - v;
        }
        __syncthreads();
        for (int i = tid; i < cnt; i += 512) {
            int e = e0 + i;
            int s, d;
            if (e < N_EDGES) { s = edge_src[e]; d = edge_dst[e]; }
            else             { s = d = e - N_EDGES; }
            int p = atomicAdd(&cur[d >> 8], 1);
            vals[p] = ((uint)(d >> 8) << 24) | ((uint)s << 8) | (uint)(d & 255);
        }
        __syncthreads();
        if (tid < NBKT && hist[tid] > 0) runbase[tid] = atomicAdd(&gcur[tid], hist[tid]);
        __syncthreads();
        for (int i = tid; i < cnt; i += 512) {
            uint v2 = vals[i];
            int b = (int)(v2 >> 24);
            int idx = runbase[b] + (i - base_l[b]);
            if (idx < CAPB) staged[b * CAPB + idx] = v2;
        }
    }
}

// ---------------------------------------------------------------------------
// P4: one block per bucket; inline bucket scan + per-node CSR.
// ---------------------------------------------------------------------------
__global__ __launch_bounds__(256) void bucket_build(const uint* __restrict__ staged,
                                                    const int* __restrict__ gcur,
                                                    int* __restrict__ row_start,
                                                    ushort* __restrict__ csr_src) {
    __shared__ int hist[256], scan_s[256], base_l[256];
    __shared__ int sBase, sCnt;
    __shared__ uint lv[CAPB];
    int tid = threadIdx.x;
    int b = blockIdx.x;

    int v = (tid < NBKT) ? min(gcur[tid], CAPB) : 0;
    scan_s[tid] = v;
    __syncthreads();
    for (int off = 1; off < 256; off <<= 1) {
        int t = (tid >= off) ? scan_s[tid - off] : 0;
        __syncthreads();
        scan_s[tid] += t;
        __syncthreads();
    }
    if (tid == b) { sBase = scan_s[tid] - v; sCnt = v; }
    __syncthreads();
    int base = sBase;
    int cnt = sCnt;

    hist[tid] = 0;
    __syncthreads();
    for (int i = tid; i < cnt; i += 256) {
        uint v2 = staged[b * CAPB + i];
        lv[i] = v2;
        atomicAdd(&hist[v2 & 255], 1);
    }
    __syncthreads();
    int v0 = hist[tid];
    scan_s[tid] = v0;
    __syncthreads();
    for (int off = 1; off < 256; off <<= 1) {
        int t = (tid >= off) ? scan_s[tid - off] : 0;
        __syncthreads();
        scan_s[tid] += t;
        __syncthreads();
    }
    int excl = scan_s[tid] - v0;
    base_l[tid] = excl;
    int node = b * 256 + tid;
    if (node < N_NODES) row_start[node] = base + excl;
    __syncthreads();
    for (int i = tid; i < cnt; i += 256) {
        uint v2 = lv[i];
        int pos = base + atomicAdd(&base_l[v2 & 255], 1);
        csr_src[pos] = (ushort)((v2 >> 8) & 0xFFFFu);
    }
}

// ---------------------------------------------------------------------------
// Layer-2 GEMM (bf16 A, K=128, 128x128 tile, 512 threads): fp8 C + alpha.
// ---------------------------------------------------------------------------
__global__ __launch_bounds__(512) void gemm_mfma2(const ushort* __restrict__ A,
                                                  const ushort* __restrict__ Wt,
                                                  unsigned char* __restrict__ C8,
                                                  const float* __restrict__ a_sv,
                                                  const float* __restrict__ a_dv,
                                                  float* __restrict__ alpha_s,
                                                  float* __restrict__ alpha_d) {
    constexpr int K = 128, KC = 64, AP = 72;
    __shared__ ushort As[128 * AP];
    __shared__ ushort Bs[128 * AP];
    int tid = threadIdx.x;
    int lane = tid & 63;
    int wv = tid >> 6;
    int mrow = lane & 15;
    int quad = lane >> 4;
    int row0 = blockIdx.x * 128;
    int M = N_NODES;

    f32x4 acc[8];
#pragma unroll
    for (int t = 0; t < 8; t++) acc[t] = (f32x4){0.f, 0.f, 0.f, 0.f};

    for (int k0 = 0; k0 < K; k0 += KC) {
#pragma unroll
        for (int p = 0; p < 2; p++) {
            int c = p * 512 + tid;
            int r = c >> 3;
            int kk = (c & 7) * 8;
            int grow = row0 + r;
            uint4 v = make_uint4(0, 0, 0, 0);
            if (grow < M) v = *(const uint4*)&A[(size_t)grow * K + k0 + kk];
            *(uint4*)&As[r * AP + kk] = v;
        }
#pragma unroll
        for (int p = 0; p < 2; p++) {
            int c = p * 512 + tid;
            int n = c >> 3;
            int kk = (c & 7) * 8;
            uint4 v = *(const uint4*)&Wt[(size_t)n * K + k0 + kk];
            *(uint4*)&Bs[n * AP + kk] = v;
        }
        __syncthreads();

        const ushort* arow = &As[(wv * 16 + mrow) * AP + quad * 8];
        const ushort* brow = &Bs[mrow * AP + quad * 8];
#pragma unroll
        for (int ks = 0; ks < KC; ks += 32) {
            bf16x8 a = *(const bf16x8*)&arow[ks];
#pragma unroll
            for (int t = 0; t < 8; t++) {
                bf16x8 b = *(const bf16x8*)&brow[t * 16 * AP + ks];
                acc[t] = __builtin_amdgcn_mfma_f32_16x16x32_bf16(a, b, acc[t], 0, 0, 0);
            }
        }
        __syncthreads();
    }

    float as_r[8], ad_r[8];
#pragma unroll
    for (int t = 0; t < 8; t++) {
        int col = t * 16 + mrow;
        as_r[t] = a_sv[col];
        ad_r[t] = a_dv[col];
    }
#pragma unroll
    for (int r = 0; r < 4; r++) {
        float ps = 0.f, pd = 0.f;
#pragma unroll
        for (int t = 0; t < 8; t++) {
            ps = fmaf(acc[t][r], as_r[t], ps);
            pd = fmaf(acc[t][r], ad_r[t], pd);
        }
#pragma unroll
        for (int o = 1; o < 16; o <<= 1) {
            ps += __shfl_xor(ps, o, 64);
            pd += __shfl_xor(pd, o, 64);
        }
        int row = row0 + wv * 16 + quad * 4 + r;
        if (mrow == 0 && row < M) {
            alpha_s[row] = ps;
            alpha_d[row] = pd;
        }
    }
#pragma unroll
    for (int t = 0; t < 8; t++) {
#pragma unroll
        for (int r = 0; r < 4; r++) {
            int row = row0 + wv * 16 + quad * 4 + r;
            if (row < M) {
                float vv = acc[t][r];
                uint p8 = (uint)__builtin_amdgcn_cvt_pk_fp8_f32(vv, vv, 0, false);
                C8[(size_t)row * HID + t * 16 + mrow] = (unsigned char)(p8 & 0xFF);
            }
        }
    }
}

// ---------------------------------------------------------------------------
// GAT aggregation v5: one node per 16-lane quarter, fp8 gathers, batch-16
// (16 KB outstanding per wave). LDS coef arrays padded to 80.
// ---------------------------------------------------------------------------
__global__ __launch_bounds__(256) void gat_aggregate(const unsigned char* __restrict__ h8,
                                                     const float* __restrict__ alpha_s,
                                                     const float* __restrict__ alpha_d,
                                                     const int* __restrict__ row_start,
                                                     const ushort* __restrict__ csr_src,
                                                     const float* __restrict__ bias,
                                                     ushort* __restrict__ outbf) {
    __shared__ float exv[4][4][80];
    __shared__ uint  sov[4][4][80];
    int wv = threadIdx.x >> 6;
    int lane = threadIdx.x & 63;
    int q = lane >> 4;
    int l = lane & 15;
    int n = blockIdx.x * 16 + wv * 4 + q;
    float* exq = exv[wv][q];
    uint*  soq = sov[wv][q];

    int beg = row_start[n];
    int deg = row_start[n + 1] - beg;
    float adn = alpha_d[n];
    int c8 = l * 8;
    const char* hbase = (const char*)h8 + c8;

    float a[8];
#pragma unroll
    for (int i = 0; i < 8; i++) a[i] = 0.f;
    float ssum = 0.f;

    for (int c0 = 0; c0 < deg; c0 += 64) {
        int cnt = min(64, deg - c0);
        for (int k = l; k < 80; k += 16) {
            if (k < cnt) {
                int s = csr_src[beg + c0 + k];
                float e = alpha_s[s] + adn;
                e = (e > 0.f) ? e : e * NEG_SLOPE;
                float ex = __expf(e);
                exq[k] = ex;
                soq[k] = (uint)s * HID;
                ssum += ex;
            } else {
                exq[k] = 0.f;
                soq[k] = 0u;
            }
        }
        __builtin_amdgcn_wave_barrier();
        int cm = cnt;
        cm = max(cm, __shfl_xor(cm, 16, 64));
        cm = max(cm, __shfl_xor(cm, 32, 64));
        for (int t0 = 0; t0 < cm; t0 += 16) {
            uint off[16]; uint2 v[16]; float w[16];
#pragma unroll
            for (int b = 0; b < 16; b++) off[b] = soq[t0 + b];
#pragma unroll
            for (int b = 0; b < 16; b++) v[b] = *(const uint2*)(hbase + off[b]);
#pragma unroll
            for (int b = 0; b < 16; b++) w[b] = exq[t0 + b];
#pragma unroll
            for (int b = 0; b < 16; b++) {
                f32x2 p0 = __builtin_amdgcn_cvt_pk_f32_fp8((int)v[b].x, false);
                f32x2 p1 = __builtin_amdgcn_cvt_pk_f32_fp8((int)v[b].x, true);
                f32x2 p2 = __builtin_amdgcn_cvt_pk_f32_fp8((int)v[b].y, false);
                f32x2 p3 = __builtin_amdgcn_cvt_pk_f32_fp8((int)v[b].y, true);
                a[0] = fmaf(w[b], p0.x, a[0]); a[1] = fmaf(w[b], p0.y, a[1]);
                a[2] = fmaf(w[b], p1.x, a[2]); a[3] = fmaf(w[b], p1.y, a[3]);
                a[4] = fmaf(w[b], p2.x, a[4]); a[5] = fmaf(w[b], p2.y, a[5]);
                a[6] = fmaf(w[b], p3.x, a[6]); a[7] = fmaf(w[b], p3.y, a[7]);
            }
        }
        __builtin_amdgcn_wave_barrier();
    }

    ssum += __shfl_xor(ssum, 1, 64);
    ssum += __shfl_xor(ssum, 2, 64);
    ssum += __shfl_xor(ssum, 4, 64);
    ssum += __shfl_xor(ssum, 8, 64);
    float inv = 1.f / ssum;
    float4 b0 = *(const float4*)&bias[c8];
    float4 b1 = *(const float4*)&bias[c8 + 4];
    float o0 = fmaxf(fmaf(a[0], inv, b0.x), 0.f);
    float o1 = fmaxf(fmaf(a[1], inv, b0.y), 0.f);
    float o2 = fmaxf(fmaf(a[2], inv, b0.z), 0.f);
    float o3 = fmaxf(fmaf(a[3], inv, b0.w), 0.f);
    float o4 = fmaxf(fmaf(a[4], inv, b1.x), 0.f);
    float o5 = fmaxf(fmaf(a[5], inv, b1.y), 0.f);
    float o6 = fmaxf(fmaf(a[6], inv, b1.z), 0.f);
    float o7 = fmaxf(fmaf(a[7], inv, b1.w), 0.f);
    uint4 pk;
    pk.x = (uint)f2bf(o0) | ((uint)f2bf(o1) << 16);
    pk.y = (uint)f2bf(o2) | ((uint)f2bf(o3) << 16);
    pk.z = (uint)f2bf(o4) | ((uint)f2bf(o5) << 16);
    pk.w = (uint)f2bf(o6) | ((uint)f2bf(o7) << 16);
    *(uint4*)&outbf[(size_t)n * HID + c8] = pk;
}

// ---------------------------------------------------------------------------
// Mean pool per graph: partials (no atomics) + classifier
// ---------------------------------------------------------------------------
__global__ __launch_bounds__(128) void pool_partial(const ushort* __restrict__ h,
                                                    const int* __restrict__ gstart,
                                                    float* __restrict__ pool_p) {
    int g = blockIdx.x;
    int slice = blockIdx.y;
    int d = threadIdx.x;
    int beg = gstart[g], end = gstart[g + 1];
    float acc = 0.f;
    for (int i = beg + slice; i < end; i += 16)
        acc += bfbits2f(((uint)h[(size_t)i * HID + d]) << 16);
    pool_p[(g * 16 + slice) * HID + d] = acc;
}

__global__ __launch_bounds__(128) void classify(const float* __restrict__ pool_p,
                                                const int* __restrict__ gstart,
                                                const float* __restrict__ Wc,
                                                const float* __restrict__ bc,
                                                float* __restrict__ out) {
    int g = blockIdx.x;
    int d = threadIdx.x;
    float s = 0.f;
#pragma unroll
    for (int sl = 0; sl < 16; sl++)
        s += pool_p[(g * 16 + sl) * HID + d];
    float cnt = (float)(gstart[g + 1] - gstart[g]);
    float p = (s / fmaxf(cnt, 1.f)) * Wc[d];
    __shared__ float red[2];
    for (int o = 32; o; o >>= 1) p += __shfl_xor(p, o, 64);
    if ((d & 63) == 0) red[d >> 6] = p;
    __syncthreads();
    if (d == 0) {
        float t = red[0] + red[1] + bc[0];
        out[g] = 1.f / (1.f + expf(-t));
    }
}

// ---------------------------------------------------------------------------
extern "C" void kernel_launch(void* const* d_in, const int* in_sizes, int n_in,
                              void* d_out, int out_size, void* d_ws, size_t ws_size,
                              hipStream_t stream) {
    const float* x     = (const float*)d_in[0];
    const int*   ei    = (const int*)d_in[1];
    const int*   batch = (const int*)d_in[2];
    const float* W1    = (const float*)d_in[3];
    const float* as1   = (const float*)d_in[4];
    const float* ad1   = (const float*)d_in[5];
    const float* b1    = (const float*)d_in[6];
    const float* W2    = (const float*)d_in[7];
    const float* as2   = (const float*)d_in[8];
    const float* ad2   = (const float*)d_in[9];
    const float* b2    = (const float*)d_in[10];
    const float* Wc    = (const float*)d_in[11];
    const float* bc    = (const float*)d_in[12];
    float* out = (float*)d_out;

    char* p = (char*)d_ws;
    auto alloc = [&](size_t bytes) {
        void* r = (void*)p;
        p += (bytes + 255) & ~(size_t)255;
        return r;
    };
    unsigned char* h8 = (unsigned char*)alloc((size_t)N_NODES * HID); // fp8 gemm out
    ushort* h1     = (ushort*)alloc((size_t)N_NODES * HID * 2);       // agg1 out (bf16)
    ushort* h0     = (ushort*)alloc((size_t)N_NODES * HID * 2);       // agg2 out (bf16)
    float*  alS    = (float*)alloc((size_t)N_NODES * 4);
    float*  alD    = (float*)alloc((size_t)N_NODES * 4);
    uint*   staged = (uint*)alloc((size_t)NBKT * CAPB * 4);           // 4.8 MB
    ushort* csr    = (ushort*)alloc((size_t)E_TOT * 2);               // 1.7 MB
    int*    rstart = (int*)alloc((size_t)(N_NODES + 1) * 4);
    int*    gcur   = (int*)alloc((NBKT + 1) * 4);
    int*    gstart = (int*)alloc((N_GRAPHS + 1) * 4);
    float*  pool_p = (float*)alloc((size_t)N_GRAPHS * 16 * HID * 4);
    ushort* Wt1    = (ushort*)alloc((size_t)128 * 256 * 2);
    ushort* Wt2    = (ushort*)alloc((size_t)128 * 128 * 2);

    const int* edge_src = ei;
    const int* edge_dst = ei + N_EDGES;

    // 1. Prep
    prep<<<388, 256, 0, stream>>>(W1, W2, Wt1, Wt2, gcur, batch, gstart, rstart);
    // 2. Layer-1 GEMM || radix scatter
    gemm1_scatter<<<NBG + NB3, 512, 0, stream>>>(
        x, Wt1, h8, as1, ad1, alS, alD, edge_src, edge_dst, gcur, staged);
    // 3. CSR finalize
    bucket_build<<<NBKT, 256, 0, stream>>>(staged, gcur, rstart, csr);
    // 4. Layer-1 aggregate (fp8 gather)
    gat_aggregate<<<N_NODES / 16, 256, 0, stream>>>(h8, alS, alD, rstart, csr, b1, h1);
    // 5. Layer-2 GEMM
    gemm_mfma2<<<NBG, 512, 0, stream>>>(h1, Wt2, h8, as2, ad2, alS, alD);
    // 6. Layer-2 aggregate (fp8 gather)
    gat_aggregate<<<N_NODES / 16, 256, 0, stream>>>(h8, alS, alD, rstart, csr, b2, h0);
    // 7-8. Pool + classify
    pool_partial<<<dim3(N_GRAPHS, 16), HID, 0, stream>>>(h0, gstart, pool_p);
    classify<<<N_GRAPHS, HID, 0, stream>>>(pool_p, gstart, Wc, bc, out);
}

// Round 12
// 206.473 us; speedup vs baseline: 1.0126x; 1.0126x over previous
//
#include <hip/hip_runtime.h>
#include <hip/hip_bf16.h>
#include <math.h>

// Problem constants (from reference)
#define N_NODES 50000
#define N_EDGES 800000
#define E_TOT   (N_EDGES + N_NODES)   // edges + self loops = 850000
#define HID     128
#define N_GRAPHS 64
#define NEG_SLOPE 0.2f

// Radix partition params
#define NBKT 196                      // buckets of 256 dst nodes
#define CAPB 6144                     // fixed bucket capacity (mean 4337, +27 sigma)
#define CHUNK3 4096
#define NB3  ((E_TOT + CHUNK3 - 1) / CHUNK3)    // 208
#define NBG1 ((N_NODES + 63) / 64)              // 782 gemm blocks

typedef __attribute__((ext_vector_type(8))) short bf16x8;
typedef __attribute__((ext_vector_type(4))) float f32x4;
typedef __attribute__((ext_vector_type(2))) float f32x2;

__device__ __forceinline__ ushort f2bf(float f) {
    union { float f; uint u; } x; x.f = f;
    uint r = x.u + 0x7fffu + ((x.u >> 16) & 1u);   // round-to-nearest-even
    return (ushort)(r >> 16);
}
__device__ __forceinline__ float bfbits2f(uint bits_hi) {
    union { uint u; float f; } x; x.u = bits_hi;
    return x.f;
}

// ---------------------------------------------------------------------------
// Prep: weight convert+transpose, gcur zero, graph bounds, row_start[N]=E_TOT.
// ---------------------------------------------------------------------------
__global__ __launch_bounds__(256) void prep(const float* __restrict__ W1,
                                            const float* __restrict__ W2,
                                            ushort* __restrict__ Wt1,
                                            ushort* __restrict__ Wt2,
                                            int* __restrict__ gcur,
                                            const int* __restrict__ batch,
                                            int* __restrict__ gstart,
                                            int* __restrict__ row_start) {
    int tid = threadIdx.x;
    if (blockIdx.x < 192) {
        int idx = blockIdx.x * 256 + tid;
        if (idx < 256 * 128) {
            int k = idx >> 7, n = idx & 127;
            Wt1[n * 256 + k] = f2bf(W1[idx]);
        } else if (idx < 256 * 128 + 128 * 128) {
            int j = idx - 256 * 128;
            int k = j >> 7, n = j & 127;
            Wt2[n * 128 + k] = f2bf(W2[j]);
        }
        if (idx <= NBKT) gcur[idx] = 0;
        if (idx == 0) row_start[N_NODES] = E_TOT;
    } else {
        int i = (blockIdx.x - 192) * 256 + tid;
        if (i >= N_NODES) return;
        int b  = batch[i];
        int bp = (i == 0) ? -1 : batch[i - 1];
        for (int g = bp + 1; g <= b; g++) gstart[g] = i;
        if (i == N_NODES - 1) {
            for (int g = b + 1; g <= N_GRAPHS; g++) gstart[g] = N_NODES;
        }
    }
}

// ---------------------------------------------------------------------------
// Fused dispatch: blocks 0..NBG1-1 layer-1 GEMM (fp32 A, K=256, fp8 C shadow
// + fused alpha); blocks NBG1.. bin_scatter. Shared 27.6 KB LDS union.
// ---------------------------------------------------------------------------
__global__ __launch_bounds__(256) void gemm1_scatter(const float* __restrict__ A,
                                                     const ushort* __restrict__ Wt,
                                                     unsigned char* __restrict__ C8,
                                                     const float* __restrict__ a_sv,
                                                     const float* __restrict__ a_dv,
                                                     float* __restrict__ alpha_s,
                                                     float* __restrict__ alpha_d,
                                                     const int* __restrict__ edge_src,
                                                     const int* __restrict__ edge_dst,
                                                     int* __restrict__ gcur,
                                                     uint* __restrict__ staged) {
    __shared__ char smem[27648];
    int tid = threadIdx.x;

    if (blockIdx.x < NBG1) {
        constexpr int K = 256, KC = 64, AP = 72;
        ushort* As = (ushort*)smem;
        ushort* Bs = (ushort*)(smem + 9216);
        int lane = tid & 63;
        int wv = tid >> 6;
        int mrow = lane & 15;
        int quad = lane >> 4;
        int row0 = blockIdx.x * 64;
        int M = N_NODES;

        f32x4 acc[8];
#pragma unroll
        for (int t = 0; t < 8; t++) acc[t] = (f32x4){0.f, 0.f, 0.f, 0.f};

        for (int k0 = 0; k0 < K; k0 += KC) {
#pragma unroll
            for (int p = 0; p < 2; p++) {
                int c = p * 256 + tid;
                int r = c >> 3;
                int kk = (c & 7) * 8;
                int grow = row0 + r;
                float4 v0 = make_float4(0.f, 0.f, 0.f, 0.f);
                float4 v1 = v0;
                if (grow < M) {
                    const float* src = &A[(size_t)grow * K + k0 + kk];
                    v0 = *(const float4*)src;
                    v1 = *(const float4*)(src + 4);
                }
                uint4 w;
                w.x = (uint)f2bf(v0.x) | ((uint)f2bf(v0.y) << 16);
                w.y = (uint)f2bf(v0.z) | ((uint)f2bf(v0.w) << 16);
                w.z = (uint)f2bf(v1.x) | ((uint)f2bf(v1.y) << 16);
                w.w = (uint)f2bf(v1.z) | ((uint)f2bf(v1.w) << 16);
                *(uint4*)&As[r * AP + kk] = w;
            }
#pragma unroll
            for (int p = 0; p < 4; p++) {
                int c = p * 256 + tid;
                int n = c >> 3;
                int kk = (c & 7) * 8;
                uint4 v = *(const uint4*)&Wt[(size_t)n * K + k0 + kk];
                *(uint4*)&Bs[n * AP + kk] = v;
            }
            __syncthreads();

            const ushort* arow = &As[(wv * 16 + mrow) * AP + quad * 8];
            const ushort* brow = &Bs[mrow * AP + quad * 8];
#pragma unroll
            for (int ks = 0; ks < KC; ks += 32) {
                bf16x8 a = *(const bf16x8*)&arow[ks];
#pragma unroll
                for (int t = 0; t < 8; t++) {
                    bf16x8 b = *(const bf16x8*)&brow[t * 16 * AP + ks];
                    acc[t] = __builtin_amdgcn_mfma_f32_16x16x32_bf16(a, b, acc[t], 0, 0, 0);
                }
            }
            __syncthreads();
        }

        float as_r[8], ad_r[8];
#pragma unroll
        for (int t = 0; t < 8; t++) {
            int col = t * 16 + mrow;
            as_r[t] = a_sv[col];
            ad_r[t] = a_dv[col];
        }
#pragma unroll
        for (int r = 0; r < 4; r++) {
            float ps = 0.f, pd = 0.f;
#pragma unroll
            for (int t = 0; t < 8; t++) {
                ps = fmaf(acc[t][r], as_r[t], ps);
                pd = fmaf(acc[t][r], ad_r[t], pd);
            }
#pragma unroll
            for (int o = 1; o < 16; o <<= 1) {
                ps += __shfl_xor(ps, o, 64);
                pd += __shfl_xor(pd, o, 64);
            }
            int row = row0 + wv * 16 + quad * 4 + r;
            if (mrow == 0 && row < M) {
                alpha_s[row] = ps;
                alpha_d[row] = pd;
            }
        }
        // fp8 e4m3 shadow only (gathers read fp8; no bf16 copy needed)
#pragma unroll
        for (int t = 0; t < 8; t++) {
#pragma unroll
            for (int r = 0; r < 4; r++) {
                int row = row0 + wv * 16 + quad * 4 + r;
                if (row < M) {
                    float vv = acc[t][r];
                    uint p8 = (uint)__builtin_amdgcn_cvt_pk_fp8_f32(vv, vv, 0, false);
                    C8[(size_t)row * HID + t * 16 + mrow] = (unsigned char)(p8 & 0xFF);
                }
            }
        }
    } else {
        int* hist    = (int*)smem;
        int* scan_s  = hist + 256;
        int* base_l  = scan_s + 256;
        int* cur     = base_l + 256;
        int* runbase = cur + 256;
        uint* vals   = (uint*)(runbase + 256);

        int e0 = (blockIdx.x - NBG1) * CHUNK3;
        int cnt = min(CHUNK3, E_TOT - e0);

        hist[tid] = 0;
        __syncthreads();
        for (int i = tid; i < cnt; i += 256) {
            int e = e0 + i;
            int d = (e < N_EDGES) ? edge_dst[e] : (e - N_EDGES);
            atomicAdd(&hist[d >> 8], 1);
        }
        __syncthreads();
        int v = hist[tid];
        scan_s[tid] = v;
        __syncthreads();
        for (int off = 1; off < 256; off <<= 1) {
            int t = (tid >= off) ? scan_s[tid - off] : 0;
            __syncthreads();
            scan_s[tid] += t;
            __syncthreads();
        }
        base_l[tid] = scan_s[tid] - v;
        cur[tid] = scan_s[tid] - v;
        __syncthreads();
        for (int i = tid; i < cnt; i += 256) {
            int e = e0 + i;
            int s, d;
            if (e < N_EDGES) { s = edge_src[e]; d = edge_dst[e]; }
            else             { s = d = e - N_EDGES; }
            int p = atomicAdd(&cur[d >> 8], 1);
            vals[p] = ((uint)(d >> 8) << 24) | ((uint)s << 8) | (uint)(d & 255);
        }
        __syncthreads();
        if (tid < NBKT && hist[tid] > 0) runbase[tid] = atomicAdd(&gcur[tid], hist[tid]);
        __syncthreads();
        for (int i = tid; i < cnt; i += 256) {
            uint v2 = vals[i];
            int b = (int)(v2 >> 24);
            int idx = runbase[b] + (i - base_l[b]);
            if (idx < CAPB) staged[b * CAPB + idx] = v2;
        }
    }
}

// ---------------------------------------------------------------------------
// P4: one block per bucket; inline bucket scan + per-node CSR.
// ---------------------------------------------------------------------------
__global__ __launch_bounds__(256) void bucket_build(const uint* __restrict__ staged,
                                                    const int* __restrict__ gcur,
                                                    int* __restrict__ row_start,
                                                    ushort* __restrict__ csr_src) {
    __shared__ int hist[256], scan_s[256], base_l[256];
    __shared__ int sBase, sCnt;
    __shared__ uint lv[CAPB];
    int tid = threadIdx.x;
    int b = blockIdx.x;

    int v = (tid < NBKT) ? min(gcur[tid], CAPB) : 0;
    scan_s[tid] = v;
    __syncthreads();
    for (int off = 1; off < 256; off <<= 1) {
        int t = (tid >= off) ? scan_s[tid - off] : 0;
        __syncthreads();
        scan_s[tid] += t;
        __syncthreads();
    }
    if (tid == b) { sBase = scan_s[tid] - v; sCnt = v; }
    __syncthreads();
    int base = sBase;
    int cnt = sCnt;

    hist[tid] = 0;
    __syncthreads();
    for (int i = tid; i < cnt; i += 256) {
        uint v2 = staged[b * CAPB + i];
        lv[i] = v2;
        atomicAdd(&hist[v2 & 255], 1);
    }
    __syncthreads();
    int v0 = hist[tid];
    scan_s[tid] = v0;
    __syncthreads();
    for (int off = 1; off < 256; off <<= 1) {
        int t = (tid >= off) ? scan_s[tid - off] : 0;
        __syncthreads();
        scan_s[tid] += t;
        __syncthreads();
    }
    int excl = scan_s[tid] - v0;
    base_l[tid] = excl;
    int node = b * 256 + tid;
    if (node < N_NODES) row_start[node] = base + excl;
    __syncthreads();
    for (int i = tid; i < cnt; i += 256) {
        uint v2 = lv[i];
        int pos = base + atomicAdd(&base_l[v2 & 255], 1);
        csr_src[pos] = (ushort)((v2 >> 8) & 0xFFFFu);
    }
}

// ---------------------------------------------------------------------------
// Layer-2 GEMM (bf16 A, K=128): fp8 C shadow + fused alpha.
// ---------------------------------------------------------------------------
__global__ __launch_bounds__(256) void gemm_mfma2(const ushort* __restrict__ A,
                                                  const ushort* __restrict__ Wt,
                                                  unsigned char* __restrict__ C8,
                                                  const float* __restrict__ a_sv,
                                                  const float* __restrict__ a_dv,
                                                  float* __restrict__ alpha_s,
                                                  float* __restrict__ alpha_d) {
    constexpr int K = 128, KC = 64, AP = 72;
    __shared__ ushort As[64 * AP];
    __shared__ ushort Bs[128 * AP];
    int tid = threadIdx.x;
    int lane = tid & 63;
    int wv = tid >> 6;
    int mrow = lane & 15;
    int quad = lane >> 4;
    int row0 = blockIdx.x * 64;
    int M = N_NODES;

    f32x4 acc[8];
#pragma unroll
    for (int t = 0; t < 8; t++) acc[t] = (f32x4){0.f, 0.f, 0.f, 0.f};

    for (int k0 = 0; k0 < K; k0 += KC) {
#pragma unroll
        for (int p = 0; p < 2; p++) {
            int c = p * 256 + tid;
            int r = c >> 3;
            int kk = (c & 7) * 8;
            int grow = row0 + r;
            uint4 v = make_uint4(0, 0, 0, 0);
            if (grow < M) v = *(const uint4*)&A[(size_t)grow * K + k0 + kk];
            *(uint4*)&As[r * AP + kk] = v;
        }
#pragma unroll
        for (int p = 0; p < 4; p++) {
            int c = p * 256 + tid;
            int n = c >> 3;
            int kk = (c & 7) * 8;
            uint4 v = *(const uint4*)&Wt[(size_t)n * K + k0 + kk];
            *(uint4*)&Bs[n * AP + kk] = v;
        }
        __syncthreads();

        const ushort* arow = &As[(wv * 16 + mrow) * AP + quad * 8];
        const ushort* brow = &Bs[mrow * AP + quad * 8];
#pragma unroll
        for (int ks = 0; ks < KC; ks += 32) {
            bf16x8 a = *(const bf16x8*)&arow[ks];
#pragma unroll
            for (int t = 0; t < 8; t++) {
                bf16x8 b = *(const bf16x8*)&brow[t * 16 * AP + ks];
                acc[t] = __builtin_amdgcn_mfma_f32_16x16x32_bf16(a, b, acc[t], 0, 0, 0);
            }
        }
        __syncthreads();
    }

    float as_r[8], ad_r[8];
#pragma unroll
    for (int t = 0; t < 8; t++) {
        int col = t * 16 + mrow;
        as_r[t] = a_sv[col];
        ad_r[t] = a_dv[col];
    }
#pragma unroll
    for (int r = 0; r < 4; r++) {
        float ps = 0.f, pd = 0.f;
#pragma unroll
        for (int t = 0; t < 8; t++) {
            ps = fmaf(acc[t][r], as_r[t], ps);
            pd = fmaf(acc[t][r], ad_r[t], pd);
        }
#pragma unroll
        for (int o = 1; o < 16; o <<= 1) {
            ps += __shfl_xor(ps, o, 64);
            pd += __shfl_xor(pd, o, 64);
        }
        int row = row0 + wv * 16 + quad * 4 + r;
        if (mrow == 0 && row < M) {
            alpha_s[row] = ps;
            alpha_d[row] = pd;
        }
    }
#pragma unroll
    for (int t = 0; t < 8; t++) {
#pragma unroll
        for (int r = 0; r < 4; r++) {
            int row = row0 + wv * 16 + quad * 4 + r;
            if (row < M) {
                float vv = acc[t][r];
                uint p8 = (uint)__builtin_amdgcn_cvt_pk_fp8_f32(vv, vv, 0, false);
                C8[(size_t)row * HID + t * 16 + mrow] = (unsigned char)(p8 & 0xFF);
            }
        }
    }
}

// ---------------------------------------------------------------------------
// GAT aggregation v4 (R10 winner): one node per 16-lane quarter, batch-8,
// unnormalized accumulate, fp8 gathers (uint2 = full 128B fp8 row/quarter).
// ---------------------------------------------------------------------------
__global__ __launch_bounds__(256) void gat_aggregate(const unsigned char* __restrict__ h8,
                                                     const float* __restrict__ alpha_s,
                                                     const float* __restrict__ alpha_d,
                                                     const int* __restrict__ row_start,
                                                     const ushort* __restrict__ csr_src,
                                                     const float* __restrict__ bias,
                                                     ushort* __restrict__ outbf) {
    __shared__ float exv[4][4][72];
    __shared__ uint  sov[4][4][72];
    int wv = threadIdx.x >> 6;
    int lane = threadIdx.x & 63;
    int q = lane >> 4;
    int l = lane & 15;
    int n = blockIdx.x * 16 + wv * 4 + q;
    float* exq = exv[wv][q];
    uint*  soq = sov[wv][q];

    int beg = row_start[n];
    int deg = row_start[n + 1] - beg;
    float adn = alpha_d[n];
    int c8 = l * 8;
    const char* hbase = (const char*)h8 + c8;

    float a[8];
#pragma unroll
    for (int i = 0; i < 8; i++) a[i] = 0.f;
    float ssum = 0.f;

    for (int c0 = 0; c0 < deg; c0 += 64) {
        int cnt = min(64, deg - c0);
        for (int k = l; k < 72; k += 16) {
            if (k < cnt) {
                int s = csr_src[beg + c0 + k];
                float e = alpha_s[s] + adn;
                e = (e > 0.f) ? e : e * NEG_SLOPE;
                float ex = __expf(e);
                exq[k] = ex;
                soq[k] = (uint)s * HID;
                ssum += ex;
            } else {
                exq[k] = 0.f;
                soq[k] = 0u;
            }
        }
        __builtin_amdgcn_wave_barrier();
        int cm = cnt;
        cm = max(cm, __shfl_xor(cm, 16, 64));
        cm = max(cm, __shfl_xor(cm, 32, 64));
        for (int t0 = 0; t0 < cm; t0 += 8) {
            uint off[8]; uint2 v[8]; float w[8];
#pragma unroll
            for (int b = 0; b < 8; b++) off[b] = soq[t0 + b];
#pragma unroll
            for (int b = 0; b < 8; b++) v[b] = *(const uint2*)(hbase + off[b]);
#pragma unroll
            for (int b = 0; b < 8; b++) w[b] = exq[t0 + b];
#pragma unroll
            for (int b = 0; b < 8; b++) {
                f32x2 p0 = __builtin_amdgcn_cvt_pk_f32_fp8((int)v[b].x, false);
                f32x2 p1 = __builtin_amdgcn_cvt_pk_f32_fp8((int)v[b].x, true);
                f32x2 p2 = __builtin_amdgcn_cvt_pk_f32_fp8((int)v[b].y, false);
                f32x2 p3 = __builtin_amdgcn_cvt_pk_f32_fp8((int)v[b].y, true);
                a[0] = fmaf(w[b], p0.x, a[0]); a[1] = fmaf(w[b], p0.y, a[1]);
                a[2] = fmaf(w[b], p1.x, a[2]); a[3] = fmaf(w[b], p1.y, a[3]);
                a[4] = fmaf(w[b], p2.x, a[4]); a[5] = fmaf(w[b], p2.y, a[5]);
                a[6] = fmaf(w[b], p3.x, a[6]); a[7] = fmaf(w[b], p3.y, a[7]);
            }
        }
        __builtin_amdgcn_wave_barrier();
    }

    ssum += __shfl_xor(ssum, 1, 64);
    ssum += __shfl_xor(ssum, 2, 64);
    ssum += __shfl_xor(ssum, 4, 64);
    ssum += __shfl_xor(ssum, 8, 64);
    float inv = 1.f / ssum;
    float4 b0 = *(const float4*)&bias[c8];
    float4 b1 = *(const float4*)&bias[c8 + 4];
    float o0 = fmaxf(fmaf(a[0], inv, b0.x), 0.f);
    float o1 = fmaxf(fmaf(a[1], inv, b0.y), 0.f);
    float o2 = fmaxf(fmaf(a[2], inv, b0.z), 0.f);
    float o3 = fmaxf(fmaf(a[3], inv, b0.w), 0.f);
    float o4 = fmaxf(fmaf(a[4], inv, b1.x), 0.f);
    float o5 = fmaxf(fmaf(a[5], inv, b1.y), 0.f);
    float o6 = fmaxf(fmaf(a[6], inv, b1.z), 0.f);
    float o7 = fmaxf(fmaf(a[7], inv, b1.w), 0.f);
    uint4 pk;
    pk.x = (uint)f2bf(o0) | ((uint)f2bf(o1) << 16);
    pk.y = (uint)f2bf(o2) | ((uint)f2bf(o3) << 16);
    pk.z = (uint)f2bf(o4) | ((uint)f2bf(o5) << 16);
    pk.w = (uint)f2bf(o6) | ((uint)f2bf(o7) << 16);
    *(uint4*)&outbf[(size_t)n * HID + c8] = pk;
}

// ---------------------------------------------------------------------------
// Mean pool per graph: partials (no atomics) + classifier
// ---------------------------------------------------------------------------
__global__ __launch_bounds__(128) void pool_partial(const ushort* __restrict__ h,
                                                    const int* __restrict__ gstart,
                                                    float* __restrict__ pool_p) {
    int g = blockIdx.x;
    int slice = blockIdx.y;
    int d = threadIdx.x;
    int beg = gstart[g], end = gstart[g + 1];
    float acc = 0.f;
    for (int i = beg + slice; i < end; i += 16)
        acc += bfbits2f(((uint)h[(size_t)i * HID + d]) << 16);
    pool_p[(g * 16 + slice) * HID + d] = acc;
}

__global__ __launch_bounds__(128) void classify(const float* __restrict__ pool_p,
                                                const int* __restrict__ gstart,
                                                const float* __restrict__ Wc,
                                                const float* __restrict__ bc,
                                                float* __restrict__ out) {
    int g = blockIdx.x;
    int d = threadIdx.x;
    float s = 0.f;
#pragma unroll
    for (int sl = 0; sl < 16; sl++)
        s += pool_p[(g * 16 + sl) * HID + d];
    float cnt = (float)(gstart[g + 1] - gstart[g]);
    float p = (s / fmaxf(cnt, 1.f)) * Wc[d];
    __shared__ float red[2];
    for (int o = 32; o; o >>= 1) p += __shfl_xor(p, o, 64);
    if ((d & 63) == 0) red[d >> 6] = p;
    __syncthreads();
    if (d == 0) {
        float t = red[0] + red[1] + bc[0];
        out[g] = 1.f / (1.f + expf(-t));
    }
}

// ---------------------------------------------------------------------------
extern "C" void kernel_launch(void* const* d_in, const int* in_sizes, int n_in,
                              void* d_out, int out_size, void* d_ws, size_t ws_size,
                              hipStream_t stream) {
    const float* x     = (const float*)d_in[0];
    const int*   ei    = (const int*)d_in[1];
    const int*   batch = (const int*)d_in[2];
    const float* W1    = (const float*)d_in[3];
    const float* as1   = (const float*)d_in[4];
    const float* ad1   = (const float*)d_in[5];
    const float* b1    = (const float*)d_in[6];
    const float* W2    = (const float*)d_in[7];
    const float* as2   = (const float*)d_in[8];
    const float* ad2   = (const float*)d_in[9];
    const float* b2    = (const float*)d_in[10];
    const float* Wc    = (const float*)d_in[11];
    const float* bc    = (const float*)d_in[12];
    float* out = (float*)d_out;

    char* p = (char*)d_ws;
    auto alloc = [&](size_t bytes) {
        void* r = (void*)p;
        p += (bytes + 255) & ~(size_t)255;
        return r;
    };
    unsigned char* h8 = (unsigned char*)alloc((size_t)N_NODES * HID); // fp8 gemm out (both layers)
    ushort* h1     = (ushort*)alloc((size_t)N_NODES * HID * 2);       // agg1 out (bf16)
    ushort* h0     = (ushort*)alloc((size_t)N_NODES * HID * 2);       // agg2 out (bf16)
    float*  alS    = (float*)alloc((size_t)N_NODES * 4);
    float*  alD    = (float*)alloc((size_t)N_NODES * 4);
    uint*   staged = (uint*)alloc((size_t)NBKT * CAPB * 4);           // 4.8 MB
    ushort* csr    = (ushort*)alloc((size_t)E_TOT * 2);               // 1.7 MB
    int*    rstart = (int*)alloc((size_t)(N_NODES + 1) * 4);
    int*    gcur   = (int*)alloc((NBKT + 1) * 4);
    int*    gstart = (int*)alloc((N_GRAPHS + 1) * 4);
    float*  pool_p = (float*)alloc((size_t)N_GRAPHS * 16 * HID * 4);
    ushort* Wt1    = (ushort*)alloc((size_t)128 * 256 * 2);
    ushort* Wt2    = (ushort*)alloc((size_t)128 * 128 * 2);

    const int* edge_src = ei;
    const int* edge_dst = ei + N_EDGES;

    // 1. Prep
    prep<<<388, 256, 0, stream>>>(W1, W2, Wt1, Wt2, gcur, batch, gstart, rstart);
    // 2. Layer-1 GEMM || radix scatter
    gemm1_scatter<<<NBG1 + NB3, 256, 0, stream>>>(
        x, Wt1, h8, as1, ad1, alS, alD, edge_src, edge_dst, gcur, staged);
    // 3. CSR finalize
    bucket_build<<<NBKT, 256, 0, stream>>>(staged, gcur, rstart, csr);
    // 4. Layer-1 aggregate (fp8 gather)
    gat_aggregate<<<N_NODES / 16, 256, 0, stream>>>(h8, alS, alD, rstart, csr, b1, h1);
    // 5. Layer-2 GEMM
    gemm_mfma2<<<NBG1, 256, 0, stream>>>(h1, Wt2, h8, as2, ad2, alS, alD);
    // 6. Layer-2 aggregate (fp8 gather)
    gat_aggregate<<<N_NODES / 16, 256, 0, stream>>>(h8, alS, alD, rstart, csr, b2, h0);
    // 7-8. Pool + classify
    pool_partial<<<dim3(N_GRAPHS, 16), HID, 0, stream>>>(h0, gstart, pool_p);
    classify<<<N_GRAPHS, HID, 0, stream>>>(pool_p, gstart, Wc, bc, out);
}